// Round 8
// baseline (536.152 us; speedup 1.0000x reference)
//
#include <hip/hip_runtime.h>
#include <cstdint>

// Problem constants (B,S,D,H) from the reference
#define B_ 64
#define S_ 2048
#define D_ 512
#define H_ 512

using f32x4  = __attribute__((ext_vector_type(4))) float;
using bf16x8 = __attribute__((ext_vector_type(8))) short;
using u32x2  = __attribute__((ext_vector_type(2))) unsigned int;

__device__ __forceinline__ unsigned short f2bf(float f) {
  unsigned u = __float_as_uint(f);
  u += 0x7FFFu + ((u >> 16) & 1u);   // round-to-nearest-even
  return (unsigned short)(u >> 16);
}
// packed f32x2 -> bf16x2 (RTE), hardware op
__device__ __forceinline__ unsigned int cvtpk(float lo, float hi) {
  unsigned int r;
  asm("v_cvt_pk_bf16_f32 %0, %1, %2" : "=v"(r) : "v"(lo), "v"(hi));
  return r;
}
// tanh via v_exp_f32: 1 - 2/(exp2(2x*log2e)+1); exact saturation at +-inf
__device__ __forceinline__ float fast_tanh(float x) {
  float t = __builtin_amdgcn_exp2f(x * 2.8853900817779268f);
  return 1.0f - 2.0f * __builtin_amdgcn_rcpf(t + 1.0f);
}

__device__ __forceinline__ void barrier_raw() {
  asm volatile("" ::: "memory");
  __builtin_amdgcn_s_barrier();
  asm volatile("" ::: "memory");
}

// ---------------------------------------------------------------------------
// k_prep: blocks [0,128): di[b,h] = hidden[b,:].Wd[h,:] + bd[h]
//         blocks [128,256): We fp32 -> bf16 (32768 chunks of 8)
__global__ void k_prep(const float* __restrict__ hidden, const float* __restrict__ Wd,
                       const float* __restrict__ bd, float* __restrict__ di,
                       const float* __restrict__ We, unsigned short* __restrict__ Web) {
  if (blockIdx.x < 128) {
    int idx = blockIdx.x * 256 + threadIdx.x;   // 32768 total
    int h = idx >> 6;
    int b = idx & 63;
    const f32x4* hp = (const f32x4*)(hidden + (size_t)b * D_);
    const f32x4* wp = (const f32x4*)(Wd + (size_t)h * D_);
    float acc = 0.f;
#pragma unroll 8
    for (int i = 0; i < D_ / 4; ++i) {
      f32x4 x = hp[i], y = wp[i];
      acc += x[0] * y[0] + x[1] * y[1] + x[2] * y[2] + x[3] * y[3];
    }
    di[b * H_ + h] = acc + bd[h];
  } else {
    int i = (blockIdx.x - 128) * 256 + threadIdx.x;   // 32768 chunks
    const f32x4* p = (const f32x4*)(We + (size_t)i * 8);
    f32x4 a = p[0], b = p[1];
    bf16x8 o;
    o[0] = (short)f2bf(a[0]); o[1] = (short)f2bf(a[1]);
    o[2] = (short)f2bf(a[2]); o[3] = (short)f2bf(a[3]);
    o[4] = (short)f2bf(b[0]); o[5] = (short)f2bf(b[1]);
    o[6] = (short)f2bf(b[2]); o[7] = (short)f2bf(b[3]);
    *(bf16x8*)(Web + (size_t)i * 8) = o;
  }
}

// ---------------------------------------------------------------------------
// ei-GEMM, templated for ablation (rule #19: co-compiled variants, within-probe
// deltas reliable).  V=0: production (R7 structure).  V=1: NO global loads in
// the k-loop (prologue only; loop = barrier+ds_read+MFMA+ds_write of stale
// regs) -- isolates the global path.  V=4: MFMA+barrier only (no LDS traffic,
// frags constant; LDS kept allocated) -- structure floor.  REPS repeats the
// whole 16-kstep loop (variant outputs are numerically garbage -> dump).
template <int V, int REPS>
__global__ __launch_bounds__(256, 3) void k_gemm(
    const float* __restrict__ A, const unsigned short* __restrict__ Bw,
    const float* __restrict__ be, const float* __restrict__ Vv,
    const float* __restrict__ di, float* __restrict__ out4) {
  __shared__ __align__(16) unsigned short ldsA[2][128 * 32];   // 8KB each
  __shared__ __align__(16) unsigned short ldsB[2][128 * 32];
  __shared__ float ured[4][64];

  const int bid = blockIdx.x;
  const int swz = (bid & 7) * 512 + (bid >> 3);   // bijective XCD chunking (4096%8==0)
  const int row0 = (swz >> 2) << 7;               // 1024 m-tiles of 128 rows
  const int nt   = swz & 3;
  const int col0 = nt << 7;

  const int t  = threadIdx.x;
  const int l  = t & 63;
  const int w  = t >> 6;          // 4 waves, 2M x 2N
  const int wm = (w >> 1) << 6;
  const int wn = (w & 1) << 6;
  const int lr = l & 15;
  const int lg = l >> 4;

  // staging maps (A fp32 rows of 128B; B bf16 rows of 64B)
  const float* gA = A + (size_t)(row0 + w * 32 + (l >> 3)) * D_ + ((l & 7) << 2);
  const unsigned short* gB = Bw + (size_t)(col0 + w * 32 + (l >> 2)) * D_ + ((l & 3) << 3);

  // LDS write slots (16B granules, phys = logical ^ ((row>>1)&3))
  const int sA = (((l & 7) >> 1) ^ ((l >> 4) & 3));
  const int eA0 = (w * 32 + (l >> 3)) * 32 + sA * 8 + (l & 1) * 4;
  const int sB = ((l & 3) ^ ((l >> 3) & 3));
  const int eB0 = (w * 32 + (l >> 2)) * 32 + sB * 8;
  const int rs = (lg ^ ((lr >> 1) & 3)) << 3;

  // two named staging register sets (rule #20)
  f32x4  rA0a, rA1a, rA2a, rA3a;  bf16x8 rB0a, rB1a;
  f32x4  rA0b, rA1b, rA2b, rA3b;  bf16x8 rB0b, rB1b;

#define LOADN(S, kk) do {                               \
    const float* a_ = gA + ((kk) << 5);                 \
    rA0##S = *(const f32x4*)(a_);                       \
    rA1##S = *(const f32x4*)(a_ + 8 * D_);              \
    rA2##S = *(const f32x4*)(a_ + 16 * D_);             \
    rA3##S = *(const f32x4*)(a_ + 24 * D_);             \
    const unsigned short* b_ = gB + ((kk) << 5);        \
    rB0##S = *(const bf16x8*)(b_);                      \
    rB1##S = *(const bf16x8*)(b_ + 16 * D_);            \
  } while (0)

#define WRITEN(S, bf) do {                                                  \
    u32x2 p0 = {cvtpk(rA0##S[0], rA0##S[1]), cvtpk(rA0##S[2], rA0##S[3])};  \
    u32x2 p1 = {cvtpk(rA1##S[0], rA1##S[1]), cvtpk(rA1##S[2], rA1##S[3])};  \
    u32x2 p2 = {cvtpk(rA2##S[0], rA2##S[1]), cvtpk(rA2##S[2], rA2##S[3])};  \
    u32x2 p3 = {cvtpk(rA3##S[0], rA3##S[1]), cvtpk(rA3##S[2], rA3##S[3])};  \
    *(u32x2*)&ldsA[bf][eA0]       = p0;                                     \
    *(u32x2*)&ldsA[bf][eA0 + 256] = p1;                                     \
    *(u32x2*)&ldsA[bf][eA0 + 512] = p2;                                     \
    *(u32x2*)&ldsA[bf][eA0 + 768] = p3;                                     \
    *(bf16x8*)&ldsB[bf][eB0]       = rB0##S;                                \
    *(bf16x8*)&ldsB[bf][eB0 + 512] = rB1##S;                                \
  } while (0)

  f32x4 acc[4][4];
  const f32x4 z = {0.f, 0.f, 0.f, 0.f};
#pragma unroll
  for (int mi = 0; mi < 4; ++mi)
#pragma unroll
    for (int ni = 0; ni < 4; ++ni) acc[mi][ni] = z;

#define KBODY(bf, LD, WR) do {                                              \
    asm volatile("s_waitcnt lgkmcnt(0)" ::: "memory");                      \
    barrier_raw();                                                          \
    bf16x8 af[4], bq[4];                                                    \
    _Pragma("unroll") for (int mi = 0; mi < 4; ++mi)                        \
      af[mi] = *(const bf16x8*)&ldsA[bf][(wm + mi * 16 + lr) * 32 + rs];    \
    _Pragma("unroll") for (int ni = 0; ni < 4; ++ni)                        \
      bq[ni] = *(const bf16x8*)&ldsB[bf][(wn + ni * 16 + lr) * 32 + rs];    \
    LD;                                                                     \
    __builtin_amdgcn_s_setprio(1);                                          \
    _Pragma("unroll") for (int mi = 0; mi < 4; ++mi)                        \
      _Pragma("unroll") for (int ni = 0; ni < 4; ++ni)                      \
        acc[mi][ni] = __builtin_amdgcn_mfma_f32_16x16x32_bf16(              \
            af[mi], bq[ni], acc[mi][ni], 0, 0, 0);                          \
    __builtin_amdgcn_s_setprio(0);                                          \
    WR;                                                                     \
  } while (0)

  if constexpr (V == 4) {
    // structure floor: barriers + MFMA only; LDS kept allocated (regime match)
    LOADN(a, 0);
    if (t == 0) {
      ((volatile unsigned short*)&ldsA[0][0])[0] = 0;
      ((volatile unsigned short*)&ldsB[0][0])[0] = 0;
    }
    bf16x8 af[4], bq[4];
#pragma unroll
    for (int mi = 0; mi < 4; ++mi) { af[mi] = rB0a; bq[mi] = rB1a; }
    for (int rep = 0; rep < REPS; ++rep)
      for (int kt = 0; kt < 16; ++kt) {
        asm volatile("s_waitcnt lgkmcnt(0)" ::: "memory");
        barrier_raw();
        __builtin_amdgcn_s_setprio(1);
#pragma unroll
        for (int mi = 0; mi < 4; ++mi)
#pragma unroll
          for (int ni = 0; ni < 4; ++ni)
            acc[mi][ni] = __builtin_amdgcn_mfma_f32_16x16x32_bf16(
                af[mi], bq[ni], acc[mi][ni], 0, 0, 0);
        __builtin_amdgcn_s_setprio(0);
      }
    // keep rA* loads from being fully dead (don't care about cost; prologue only)
    asm volatile("" :: "v"(rA0a[0]), "v"(rA1a[0]), "v"(rA2a[0]), "v"(rA3a[0]));
  } else {
    // prologue: tile0 -> set a -> buf0; tile1 -> set b
    LOADN(a, 0);
    WRITEN(a, 0);
    LOADN(b, 1);
    for (int rep = 0; rep < REPS; ++rep) {
      for (int u = 0; u < 7; ++u) {
        const int kt = 2 * u;
        (void)kt;
        if constexpr (V == 0) {
          KBODY(0, LOADN(a, kt + 2), WRITEN(b, 1));
          KBODY(1, LOADN(b, kt + 3), WRITEN(a, 0));
        } else {   // V==1: no global loads in steady state; write stale regs
          KBODY(0, (void)0, WRITEN(b, 1));
          KBODY(1, (void)0, WRITEN(a, 0));
        }
      }
      KBODY(0, (void)0, WRITEN(b, 1));
      KBODY(1, (void)0, (void)0);
      if (rep + 1 < REPS) {
        if constexpr (V == 0) { LOADN(a, 0); WRITEN(a, 0); LOADN(b, 1); }
        // V==1: buffers still hold valid-enough stale data; nothing to do
      }
    }
  }
#undef KBODY
#undef LOADN
#undef WRITEN

  // fused ui partials over this block's 128 columns; atomic-free.
  const int b = row0 >> 11;
  float uacc[4][4];
#pragma unroll
  for (int mi = 0; mi < 4; ++mi)
#pragma unroll
    for (int j = 0; j < 4; ++j) uacc[mi][j] = 0.f;

#pragma unroll
  for (int ni = 0; ni < 4; ++ni) {
    const int gc = col0 + wn + ni * 16 + lr;
    const float vv = Vv[gc];
    const float base = di[b * H_ + gc] + be[gc];
#pragma unroll
    for (int mi = 0; mi < 4; ++mi)
#pragma unroll
      for (int j = 0; j < 4; ++j)
        uacc[mi][j] += vv * fast_tanh(base + acc[mi][ni][j]);
  }
#pragma unroll
  for (int mi = 0; mi < 4; ++mi)
#pragma unroll
    for (int j = 0; j < 4; ++j) {
      float s = uacc[mi][j];
      s += __shfl_xor(s, 1);
      s += __shfl_xor(s, 2);
      s += __shfl_xor(s, 4);
      s += __shfl_xor(s, 8);
      if (lr == 0) ured[w][mi * 16 + (lg << 2) + j] = s;
    }
  __syncthreads();
  if (t < 128) {
    const int r = t & 63, half = t >> 6;
    out4[nt * (B_ * S_) + row0 + half * 64 + r] =
        ured[half * 2][r] + ured[half * 2 + 1][r];
  }
}

// ---------------------------------------------------------------------------
// softmax over S per batch row: sums the 4 ui partials, applies mask -> -inf.
__global__ void k_softmax(const float* __restrict__ ui4, const void* __restrict__ mask,
                          float* __restrict__ alpha) {
  __shared__ float red[4];
  __shared__ int sfl;
  const int b = blockIdx.x, t = threadIdx.x;
  const int l = t & 63, w = t >> 6;

  if (t == 0) sfl = 0;
  const unsigned int* mw = (const unsigned int*)mask;
  unsigned det = (mw[b * 512 + t] | mw[b * 512 + 256 + t]) & 0xFFFFFF00u;
  __syncthreads();
  if (det) atomicOr(&sfl, 1);
  __syncthreads();
  const int fl = sfl;   // 1 => byte layout

  float u[8];
#pragma unroll
  for (int i = 0; i < 8; ++i) {
    const int idx = b * S_ + t + i * 256;
    const int msk = fl ? (int)((const unsigned char*)mask)[idx]
                       : ((const int*)mask)[idx];
    const float uv = ui4[idx] + ui4[idx + B_ * S_] + ui4[idx + 2 * B_ * S_] +
                     ui4[idx + 3 * B_ * S_];
    u[i] = msk ? -__builtin_inff() : uv;
  }

  float mx = u[0];
#pragma unroll
  for (int i = 1; i < 8; ++i) mx = fmaxf(mx, u[i]);
#pragma unroll
  for (int off = 32; off; off >>= 1) mx = fmaxf(mx, __shfl_xor(mx, off));
  if (l == 0) red[w] = mx;
  __syncthreads();
  mx = fmaxf(fmaxf(red[0], red[1]), fmaxf(red[2], red[3]));
  __syncthreads();

  float p[8];
  float s = 0.f;
#pragma unroll
  for (int i = 0; i < 8; ++i) {
    p[i] = __builtin_amdgcn_exp2f((u[i] - mx) * 1.4426950408889634f);
    s += p[i];
  }
#pragma unroll
  for (int off = 32; off; off >>= 1) s += __shfl_xor(s, off);
  if (l == 0) red[w] = s;
  __syncthreads();
  s = red[0] + red[1] + red[2] + red[3];

  const float inv = 1.0f / s;
#pragma unroll
  for (int i = 0; i < 8; ++i) alpha[b * S_ + t + i * 256] = p[i] * inv;
}

// ---------------------------------------------------------------------------
// part[chunk][b][d] = sum over 128 s of alpha * ctx (fp32)
__global__ void k_wsum(const float* __restrict__ ctx, const float* __restrict__ alpha,
                       float* __restrict__ part) {
  __shared__ float red[3][512];
  const int b = blockIdx.x >> 4, chunk = blockIdx.x & 15;
  const int t = threadIdx.x;
  const int h0 = (t & 63) << 3;
  const int sw = t >> 6;
  const int s0 = chunk << 7;

  float acc[8] = {0.f, 0.f, 0.f, 0.f, 0.f, 0.f, 0.f, 0.f};
#pragma unroll 2
  for (int k = 0; k < 32; ++k) {
    const int s = s0 + sw + (k << 2);
    const float a = alpha[b * S_ + s];
    const f32x4* e = (const f32x4*)(ctx + ((size_t)(b * S_ + s)) * D_ + h0);
    f32x4 e0 = e[0], e1 = e[1];
#pragma unroll
    for (int j = 0; j < 4; ++j) acc[j] += a * e0[j];
#pragma unroll
    for (int j = 0; j < 4; ++j) acc[4 + j] += a * e1[j];
  }
  if (sw) {
#pragma unroll
    for (int j = 0; j < 8; ++j) red[sw - 1][h0 + j] = acc[j];
  }
  __syncthreads();
  if (sw == 0) {
#pragma unroll
    for (int j = 0; j < 8; ++j)
      part[((chunk << 6) + b) * 512 + h0 + j] =
          acc[j] + red[0][h0 + j] + red[1][h0 + j] + red[2][h0 + j];
  }
}

// ---------------------------------------------------------------------------
// k_tail: collapse part chunks into LDS wsum, then out1 = wsum.We^T + be
__global__ void k_tail(const float* __restrict__ part, const float* __restrict__ We,
                       const float* __restrict__ be, float* __restrict__ out1) {
  __shared__ float wsum_s[512];
  const int b = blockIdx.x, t = threadIdx.x;

  float s = 0.f;
#pragma unroll
  for (int c = 0; c < 16; ++c) s += part[((c << 6) + b) * 512 + t];
  wsum_s[t] = s;
  __syncthreads();

  const f32x4* wp = (const f32x4*)wsum_s;
  const f32x4* ep = (const f32x4*)(We + (size_t)t * D_);
  float acc = 0.f;
#pragma unroll 8
  for (int i = 0; i < D_ / 4; ++i) {
    f32x4 x = wp[i], y = ep[i];
    acc += x[0] * y[0] + x[1] * y[1] + x[2] * y[2] + x[3] * y[3];
  }
  out1[b * H_ + t] = acc + be[t];
}

// ---------------------------------------------------------------------------
extern "C" void kernel_launch(void* const* d_in, const int* in_sizes, int n_in,
                              void* d_out, int out_size, void* d_ws, size_t ws_size,
                              hipStream_t stream) {
  const float* hidden = (const float*)d_in[0];
  const float* ctx    = (const float*)d_in[1];
  const void*  mask   = d_in[2];
  const float* Wd     = (const float*)d_in[3];
  const float* bd     = (const float*)d_in[4];
  const float* We     = (const float*)d_in[5];
  const float* be     = (const float*)d_in[6];
  const float* V      = (const float*)d_in[7];

  float* out   = (float*)d_out;
  float* alpha = out;               // [B,S]
  float* out1  = out + B_ * S_;     // [B,H]

  // ws layout: ui4/part (2MB) | di (128KB) | Web (512KB) | dump (2MB, diag)
  char* ws = (char*)d_ws;
  const size_t off_u2   = 0;
  const size_t off_r3   = off_u2 + 4ull * B_ * S_ * 4;     // +2 MiB
  const size_t off_web  = off_r3 + (size_t)B_ * H_ * 4;    // +128 KiB
  const size_t off_dump = off_web + (size_t)H_ * D_ * 2;   // +512 KiB

  float* ui4  = (float*)(ws + off_u2);
  float* part = (float*)(ws + off_u2);
  float* di   = (float*)(ws + off_r3);
  unsigned short* Web = (unsigned short*)(ws + off_web);
  float* dump = (float*)(ws + off_dump);

  k_prep<<<256, 256, 0, stream>>>(hidden, Wd, bd, di, We, Web);
  k_gemm<0, 1><<<(B_ * S_ / 128) * 4, 256, 0, stream>>>(ctx, Web, be, V, di, ui4);
  k_softmax<<<B_, 256, 0, stream>>>(ui4, mask, alpha);
  k_wsum<<<B_ * 16, 256, 0, stream>>>(ctx, alpha, part);
  k_tail<<<B_, 512, 0, stream>>>(part, We, be, out1);

  // ---- diagnostics (outputs -> dump; run after all real consumers) ----
  k_gemm<1, 6><<<(B_ * S_ / 128) * 4, 256, 0, stream>>>(ctx, Web, be, V, di, dump);
  k_gemm<4, 2><<<(B_ * S_ / 128) * 4, 256, 0, stream>>>(ctx, Web, be, V, di, dump);
}